// Round 17
// baseline (523.555 us; speedup 1.0000x reference)
//
#include <hip/hip_runtime.h>
#include <hip/hip_bf16.h>
#include <type_traits>
#include <utility>
#include <cmath>

// ---- problem constants ----
#define HIDDEN 4096
#define NHEADS 32
#define NKV 8
#define HD 128
#define BB 2
#define SS 2048
#define NTOK (BB*SS)                  // 4096 tokens
#define ATTN_MULT 0.08838834764831845f

using bf16x8 = __attribute__((ext_vector_type(8))) short;
using f32x4  = __attribute__((ext_vector_type(4))) float;

using gas = __attribute__((address_space(1))) const void;
using las = __attribute__((address_space(3))) void;

__device__ __forceinline__ unsigned short f2bf(float f){
  unsigned int u = __builtin_bit_cast(unsigned int, f);
  u += 0x7fffu + ((u >> 16) & 1u);
  return (unsigned short)(u >> 16);
}
__device__ __forceinline__ unsigned int cvtpk(float lo, float hi){
  unsigned int r;
  asm("v_cvt_pk_bf16_f32 %0, %1, %2" : "=v"(r) : "v"(lo), "v"(hi));
  return r;
}
__device__ __forceinline__ float exp2_hw(float x){
  float r;
  asm("v_exp_f32 %0, %1" : "=v"(r) : "v"(x));
  return r;
}

// log2e-folded soft-cap poly constants: p = 2^(s*wv + B30L), wv = L + C1L*s^2 + C2L*s^4
#define LOG2E 1.4426950408889634f
#define C1L  (-5.3433149e-4f)
#define C2L  (2.3748069e-7f)
#define B30L (-43.280851227f)

// ---- fp32 -> bf16 elementwise (8 el/thread) ----
__global__ void cvt_f32_bf16_k(const float* __restrict__ in, unsigned short* __restrict__ out, int n8){
  int i = blockIdx.x * blockDim.x + threadIdx.x;
  if (i >= n8) return;
  const float4* p = (const float4*)in + (size_t)i * 2;
  float4 a = p[0], b = p[1];
  bf16x8 o;
  o[0]=f2bf(a.x); o[1]=f2bf(a.y); o[2]=f2bf(a.z); o[3]=f2bf(a.w);
  o[4]=f2bf(b.x); o[5]=f2bf(b.y); o[6]=f2bf(b.z); o[7]=f2bf(b.w);
  ((bf16x8*)out)[i] = o;
}

// ---- W[K][N] fp32 -> WT[N][K] bf16 (tiled transpose) ----
__global__ void transpose_cvt_k(const float* __restrict__ W, unsigned short* __restrict__ WT, int K, int N){
  __shared__ float tile[32][33];
  int n0 = blockIdx.x * 32, k0 = blockIdx.y * 32;
  int tx = threadIdx.x, ty = threadIdx.y; // 32 x 8
  #pragma unroll
  for (int i = 0; i < 4; ++i)
    tile[ty*4+i][tx] = W[(size_t)(k0 + ty*4 + i) * N + n0 + tx];
  __syncthreads();
  #pragma unroll
  for (int i = 0; i < 4; ++i)
    WT[(size_t)(n0 + ty*4 + i) * K + k0 + tx] = f2bf(tile[tx][ty*4+i]);
}

// ---- bf16 KV[4096][2048] (V in cols 1024..2047) -> VT[(b*1024+c)][s] ----
__global__ void transpose_v_k(const unsigned short* __restrict__ in, unsigned short* __restrict__ out){
  __shared__ unsigned short tile[32][33];
  int c0 = blockIdx.x * 32, r0 = blockIdx.y * 32;
  int tx = threadIdx.x, ty = threadIdx.y; // 32 x 8
  #pragma unroll
  for (int i = 0; i < 4; ++i)
    tile[ty*4+i][tx] = in[(size_t)(r0 + ty*4 + i) * 2048 + 1024 + c0 + tx];
  __syncthreads();
  #pragma unroll
  for (int i = 0; i < 4; ++i){
    int c = c0 + ty*4 + i, r = r0 + tx;
    out[((size_t)((r >> 11) * 1024 + c)) * 2048 + (r & 2047)] = tile[tx][ty*4+i];
  }
}

// ---- old reliable 128x128x32 GEMM (serial stage) — used for the KV proj ----
template<typename OutT>
__global__ __launch_bounds__(256, 3)
void gemm_bt_k(const unsigned short* __restrict__ A,
               const unsigned short* __restrict__ BT,
               OutT* __restrict__ C, int M, int N, int K){
  __shared__ __align__(16) unsigned short As[128*32];
  __shared__ __align__(16) unsigned short Bs[128*32];
  const int m0 = blockIdx.y * 128, n0 = blockIdx.x * 128;
  const int tid = threadIdx.x, w = tid >> 6, lane = tid & 63;
  const int wr = w >> 1, wc = w & 1;
  const int lrow = lane & 15, lk = (lane >> 4) * 8;
  const int arow = lane >> 2, acol = (lane & 3) * 8;

  f32x4 acc[4][4] = {};

  for (int k0 = 0; k0 < K; k0 += 32){
    #pragma unroll
    for (int i = 0; i < 2; ++i){
      int chunk = w*2 + i;
      const unsigned short* ga = A  + (size_t)(m0 + chunk*16 + arow) * K + k0 + acol;
      const unsigned short* gb = BT + (size_t)(n0 + chunk*16 + arow) * K + k0 + acol;
      __builtin_amdgcn_global_load_lds((gas*)ga, (las*)(As + chunk*512), 16, 0, 0);
      __builtin_amdgcn_global_load_lds((gas*)gb, (las*)(Bs + chunk*512), 16, 0, 0);
    }
    __syncthreads();
    bf16x8 af[4], bfr[4];
    #pragma unroll
    for (int m = 0; m < 4; ++m) af[m]  = *(const bf16x8*)&As[(wr*64 + m*16 + lrow)*32 + lk];
    #pragma unroll
    for (int n = 0; n < 4; ++n) bfr[n] = *(const bf16x8*)&Bs[(wc*64 + n*16 + lrow)*32 + lk];
    #pragma unroll
    for (int m = 0; m < 4; ++m)
      #pragma unroll
      for (int n = 0; n < 4; ++n)
        acc[m][n] = __builtin_amdgcn_mfma_f32_16x16x32_bf16(af[m], bfr[n], acc[m][n], 0, 0, 0);
    __syncthreads();
  }

  const int crow = (lane >> 4) * 4, ccol = lane & 15;
  #pragma unroll
  for (int m = 0; m < 4; ++m)
    #pragma unroll
    for (int n = 0; n < 4; ++n){
      size_t base = (size_t)(m0 + wr*64 + m*16 + crow) * N + n0 + wc*64 + n*16 + ccol;
      #pragma unroll
      for (int r = 0; r < 4; ++r){
        float v = acc[m][n][r];
        if constexpr (std::is_same<OutT, unsigned short>::value) C[base + (size_t)r*N] = f2bf(v);
        else                                                     C[base + (size_t)r*N] = v;
      }
    }
}

// ---- 256x256x32 GEMM, 3-buffer LDS, 1 barrier + counted vmcnt(4) per tile ----
// Per tile t: STG(t+1 -> buf[(t+1)%3], 4 loads); vmcnt(4) retires own stage(t)
// (FIFO); s_barrier publishes all waves' stage(t); 12 ds_read; 32 MFMA.
// No drain in main loop (only final tile). WAR: stage target buffer was last
// read in tile t-2; those reads completed before the t-1 barrier (ds_read data
// consumed via lgkm before each wave's MFMAs issue). Swizzle: 16B-chunk index
// ^= (row>>1)&3 (pre-swizzled global source + swizzled read) -> 2-way = free.
#define GBAR() asm volatile("s_barrier" ::: "memory")

template<typename OutT>
__global__ __launch_bounds__(512, 2)
void gemm8_k(const unsigned short* __restrict__ A,
             const unsigned short* __restrict__ BT,
             OutT* __restrict__ C, int M, int N, int K, float scale){
  __shared__ __align__(16) unsigned short As[3][256*32];   // 48 KB
  __shared__ __align__(16) unsigned short Bs[3][256*32];   // 48 KB

  const int nbx = N >> 8;
  const int id = blockIdx.x + blockIdx.y * nbx;
  const int nwg = nbx * (M >> 8);
  const int swz = (id & 7) * (nwg >> 3) + (id >> 3);
  const int m0 = (swz / nbx) << 8, n0 = (swz % nbx) << 8;

  const int tid = threadIdx.x, w = tid >> 6, lane = tid & 63;
  const int wm = w >> 2, wn = w & 3;
  const int lrow = lane & 15, lhi = lane >> 4;
  const int NT = K >> 5;           // 128

  f32x4 acc[8][4] = {};

  // stage tile t into buffer s: 4 loads/thread (A x2, B x2), source pre-swizzled
  auto STG = [&](int t, int s){
    #pragma unroll
    for (int j = 0; j < 2; ++j){
      int c = j*512 + tid;                    // chunk 0..1023 (16B each)
      int row = c >> 2, kc = c & 3;
      int ksw = (kc ^ ((row >> 1) & 3)) << 3; // pre-swizzled k-offset (elements)
      int cbase = (j*512 + w*64) * 8;         // wave-uniform LDS base (elements)
      const unsigned short* ga = A  + (size_t)(m0 + row) * K + t*32 + ksw;
      __builtin_amdgcn_global_load_lds((gas*)ga, (las*)(&As[s][0] + cbase), 16, 0, 0);
      const unsigned short* gb = BT + (size_t)(n0 + row) * K + t*32 + ksw;
      __builtin_amdgcn_global_load_lds((gas*)gb, (las*)(&Bs[s][0] + cbase), 16, 0, 0);
    }
  };

  STG(0, 0);                      // prologue: 4 outstanding
  int cur = 0, nxt = 1;

  #pragma unroll 1
  for (int t = 0; t < NT; ++t){
    if (t + 1 < NT){
      STG(t + 1, nxt);
      asm volatile("s_waitcnt vmcnt(4)");   // retire stage(t); stage(t+1) in flight
    } else {
      asm volatile("s_waitcnt vmcnt(0)");   // final tile: drain
    }
    GBAR();

    bf16x8 bfr[4], af[8];
    #pragma unroll
    for (int nf = 0; nf < 4; ++nf){
      int row = wn*64 + nf*16 + lrow;
      int ch = lhi ^ ((row >> 1) & 3);
      bfr[nf] = *(const bf16x8*)&Bs[cur][row*32 + ch*8];
    }
    #pragma unroll
    for (int mf = 0; mf < 8; ++mf){
      int row = wm*128 + mf*16 + lrow;
      int ch = lhi ^ ((row >> 1) & 3);
      af[mf] = *(const bf16x8*)&As[cur][row*32 + ch*8];
    }
    __builtin_amdgcn_s_setprio(1);
    #pragma unroll
    for (int mf = 0; mf < 8; ++mf)
      #pragma unroll
      for (int nf = 0; nf < 4; ++nf)
        acc[mf][nf] = __builtin_amdgcn_mfma_f32_16x16x32_bf16(af[mf], bfr[nf], acc[mf][nf], 0, 0, 0);
    __builtin_amdgcn_s_setprio(0);

    cur = nxt; ++nxt; if (nxt == 3) nxt = 0;
  }

  #pragma unroll
  for (int mf = 0; mf < 8; ++mf)
    #pragma unroll
    for (int nf = 0; nf < 4; ++nf){
      size_t base = (size_t)(m0 + wm*128 + mf*16 + lhi*4) * N + n0 + wn*64 + nf*16 + lrow;
      #pragma unroll
      for (int r = 0; r < 4; ++r){
        float v = acc[mf][nf][r] * scale;
        if constexpr (std::is_same<OutT, unsigned short>::value) C[base + (size_t)r*N] = f2bf(v);
        else                                                     C[base + (size_t)r*N] = v;
      }
    }
}

// ---- causal GQA attention: 32 q-rows/wave, sequential strip pairs (R13) ----
__global__ __launch_bounds__(512, 2)
void attn_k(const unsigned short* __restrict__ Q,
            const unsigned short* __restrict__ KVp,
            const unsigned short* __restrict__ VTp,
            unsigned short* __restrict__ ctx){
  __shared__ __align__(16) unsigned short Ks[2][64*128];   // 32 KB
  __shared__ __align__(16) unsigned short Vt[2][128*64];   // 32 KB
  __shared__ __align__(16) unsigned short Ps[8][1024];     // 16 KB: per-wave [2 qg][16 q][32 kv]

  // decode: 256 blocks = 8 xcd x (2 gsub x 4 hs x 4 fi)
  const int Wb = blockIdx.x;
  const int xcd = Wb & 7, sI = Wb >> 3;          // sI 0..31
  const int gsub = sI >> 4;
  const int inner = sI & 15;
  const int hsH = inner >> 2;                     // 0..3
  const int fi = inner & 3;                       // strip-pair index 0..3
  const int group = xcd*2 + gsub;                 // 0..15 = b*8 + kvh
  const int b = group >> 3, kvh = group & 7;
  const int h = kvh*4 + hsH;

  const int tid = threadIdx.x, w = tid >> 6, lane = tid & 63;
  const int lrow = lane & 15, lhi = lane >> 4;
  const int xorv = (lrow & 3) << 4;

  const unsigned short* Kbh  = KVp + (size_t)b * SS * 2048 + kvh * HD;
  const unsigned short* VTbh = VTp + ((size_t)b * 1024 + kvh * HD) * SS;

  auto STAGE = [&](int db, int t){
    #pragma unroll
    for (int it = 0; it < 2; ++it){
      int cbase = it*512 + w*64;       // wave-uniform
      int c = cbase + lane;            // chunk 0..1023 (16B each)
      int kkv = c >> 4, kc = c & 15;
      const unsigned short* gk = Kbh + (size_t)(t*64 + kkv) * 2048 + ((kc ^ (kkv & 7)) << 3);
      __builtin_amdgcn_global_load_lds((gas*)gk, (las*)(&Ks[db][0] + cbase*8), 16, 0, 0);
      int vd = c >> 3, vc = c & 7;
      const unsigned short* gv = VTbh + (size_t)vd * SS + t*64 + ((vc ^ ((vd ^ (vd >> 3)) & 7)) << 3);
      __builtin_amdgcn_global_load_lds((gas*)gv, (las*)(&Vt[db][0] + cbase*8), 16, 0, 0);
    }
  };

  #pragma unroll 1
  for (int ph = 0; ph < 2; ++ph){
    const int strip = ph ? (7 - fi) : fi;
    const int qwb = strip*256 + w*32;             // wave's q base (32 rows)
    const int nt = strip*4 + 4;

    // Q fragments: 32 rows per wave (2 groups of 16)
    bf16x8 qf[2][4];
    {
      const unsigned short* qb = Q + (size_t)(b*SS + qwb + lrow) * 4096 + h*HD + lhi*8;
      #pragma unroll
      for (int qg = 0; qg < 2; ++qg)
        #pragma unroll
        for (int ks = 0; ks < 4; ++ks)
          qf[qg][ks] = *(const bf16x8*)(qb + (size_t)qg*16*4096 + ks*32);
    }

    f32x4 o[8][2] = {};          // O^T frag: d = df*16+lhi*4+r, q = lrow
    float psum[2] = {0.f, 0.f};

    STAGE(0, 0);
    __syncthreads();

    for (int t = 0; t < nt; ++t){
      const int db = t & 1;
      if (t + 1 < nt) STAGE(db ^ 1, t + 1);

      if (t*64 <= qwb + 31){
        const char* Kc = (const char*)&Ks[db][0];
        const char* Vc = (const char*)&Vt[db][0];
        char* Pw = (char*)&Ps[w][0];

        auto body = [&](auto DIAG){
          #pragma unroll
          for (int hh = 0; hh < 2; ++hh){
            // QK for cf = 2hh, 2hh+1: sacc[qg][cc]; lane: q=lrow, kv=cf*16+lhi*4+r
            f32x4 sacc[2][2];
            #pragma unroll
            for (int cc = 0; cc < 2; ++cc){
              const int row = (hh*2 + cc)*16 + lrow;
              bf16x8 kf[4];
              #pragma unroll
              for (int ks = 0; ks < 4; ++ks){
                int kbyte = (row*256 + (ks*32 + lhi*8)*2) ^ ((row & 7) << 4);
                kf[ks] = *(const bf16x8*)(Kc + kbyte);
              }
              f32x4 s0 = {0.f,0.f,0.f,0.f}, s1 = {0.f,0.f,0.f,0.f};
              __builtin_amdgcn_s_setprio(1);
              #pragma unroll
              for (int ks = 0; ks < 4; ++ks){
                s0 = __builtin_amdgcn_mfma_f32_16x16x32_bf16(kf[ks], qf[0][ks], s0, 0, 0, 0);
                s1 = __builtin_amdgcn_mfma_f32_16x16x32_bf16(kf[ks], qf[1][ks], s1, 0, 0, 0);
              }
              __builtin_amdgcn_s_setprio(0);
              sacc[0][cc] = s0; sacc[1][cc] = s1;
            }

            // softmax + packed b64 P writes into 2KB/wave region
            #pragma unroll
            for (int qg = 0; qg < 2; ++qg){
              const int qglob = qwb + qg*16 + lrow;
              #pragma unroll
              for (int cc = 0; cc < 2; ++cc){
                float pv[4];
                #pragma unroll
                for (int r = 0; r < 4; ++r){
                  float s = __builtin_amdgcn_fmed3f(sacc[qg][cc][r], -25.f, 25.f);
                  float s2 = s*s, s4 = s2*s2;
                  float wv = __builtin_fmaf(s2, C1L, LOG2E);
                  wv = __builtin_fmaf(s4, C2L, wv);
                  float p = exp2_hw(__builtin_fmaf(s, wv, B30L));
                  if constexpr (decltype(DIAG)::value){
                    int kvg = t*64 + (hh*2 + cc)*16 + lhi*4 + r;
                    p = (kvg <= qglob) ? p : 0.f;
                  }
                  psum[qg] += p;
                  pv[r] = p;
                }
                uint2 pk;
                pk.x = cvtpk(pv[0], pv[1]);
                pk.y = cvtpk(pv[2], pv[3]);
                *(uint2*)(Pw + qg*1024 + lrow*64 + ((cc*32 + lhi*8) ^ xorv)) = pk;
              }
            }

            // PV for this 32-kv half
            bf16x8 pf0 = *(const bf16x8*)(Pw +        lrow*64 + ((lhi*16) ^ xorv));
            bf16x8 pf1 = *(const bf16x8*)(Pw + 1024 + lrow*64 + ((lhi*16) ^ xorv));
            __builtin_amdgcn_s_setprio(1);
            #pragma unroll
            for (int df = 0; df < 8; ++df){
              int d = df*16 + lrow;
              int vbyte = (d*128 + (hh*32 + lhi*8)*2) ^ (((d ^ (d >> 3)) & 7) << 4);
              bf16x8 vf = *(const bf16x8*)(Vc + vbyte);
              o[df][0] = __builtin_amdgcn_mfma_f32_16x16x32_bf16(vf, pf0, o[df][0], 0, 0, 0);
              o[df][1] = __builtin_amdgcn_mfma_f32_16x16x32_bf16(vf, pf1, o[df][1], 0, 0, 0);
            }
            __builtin_amdgcn_s_setprio(0);
          }
        };
        if (t == (qwb >> 6)) body(std::true_type{});
        else                 body(std::false_type{});
      }
      __syncthreads();
    }

    // reduce row sums across the 4 lhi groups; normalize; packed 8B stores
    #pragma unroll
    for (int qg = 0; qg < 2; ++qg){
      float sum = psum[qg];
      sum += __shfl_xor(sum, 16);
      sum += __shfl_xor(sum, 32);
      float inv = 1.f / sum;
      unsigned short* base = ctx + (size_t)(b*SS + qwb + qg*16 + lrow) * 4096 + h*HD + lhi*4;
      #pragma unroll
      for (int df = 0; df < 8; ++df){
        uint2 pk;
        pk.x = cvtpk(o[df][qg][0] * inv, o[df][qg][1] * inv);
        pk.y = cvtpk(o[df][qg][2] * inv, o[df][qg][3] * inv);
        *(uint2*)(base + df*16) = pk;
      }
    }
    __syncthreads();   // all waves done with LDS before next phase's STAGE
  }
}

// ---- workspace layout (bytes) ----
#define O_HSB   ((size_t)0)            // 33,554,432  hs bf16 [4096][4096]
#define O_WQT   ((size_t)33554432)     // 33,554,432  WqT bf16; later reused for VT (8MB)
#define O_WKT   ((size_t)67108864)     //  8,388,608  WkT bf16 [1024][4096]
#define O_WVT   ((size_t)75497472)     //  8,388,608  WvT bf16 [1024][4096] (contiguous after WkT)
#define O_WOT   ((size_t)83886080)     // 33,554,432  WoT bf16 [4096][4096]
#define O_Q     ((size_t)117440512)    // 33,554,432  Q bf16 [4096][4096] (pre-scaled by ATTN_MULT)
#define O_KV    ((size_t)150994944)    // 16,777,216  KV bf16 [4096][2048] (K|V)
#define O_CTX   ((size_t)167772160)    // 33,554,432  ctx bf16 [4096][4096]
#define WS_NEED ((size_t)201326592)

extern "C" void kernel_launch(void* const* d_in, const int* in_sizes, int n_in,
                              void* d_out, int out_size, void* d_ws, size_t ws_size,
                              hipStream_t stream){
  if (ws_size < WS_NEED) return;
  const float* hs = (const float*)d_in[0];
  const float* Wq = (const float*)d_in[1];
  const float* Wk = (const float*)d_in[2];
  const float* Wv = (const float*)d_in[3];
  const float* Wo = (const float*)d_in[4];
  char* ws = (char*)d_ws;
  unsigned short* hsb = (unsigned short*)(ws + O_HSB);
  unsigned short* WqT = (unsigned short*)(ws + O_WQT);
  unsigned short* WkT = (unsigned short*)(ws + O_WKT);
  unsigned short* WvT = (unsigned short*)(ws + O_WVT);
  unsigned short* WoT = (unsigned short*)(ws + O_WOT);
  unsigned short* Qb  = (unsigned short*)(ws + O_Q);
  unsigned short* KVb = (unsigned short*)(ws + O_KV);
  unsigned short* ctxb= (unsigned short*)(ws + O_CTX);
  unsigned short* VTb = (unsigned short*)(ws + O_WQT);  // reuse WqT region after Q proj

  // hs -> bf16
  cvt_f32_bf16_k<<<dim3((NTOK*HIDDEN/8)/256), dim3(256), 0, stream>>>(hs, hsb, NTOK*HIDDEN/8);
  // weights -> transposed bf16 ([N][K]); WkT/WvT contiguous -> one [2048][4096]
  transpose_cvt_k<<<dim3(128,128), dim3(32,8), 0, stream>>>(Wq, WqT, 4096, 4096);
  transpose_cvt_k<<<dim3(32,128),  dim3(32,8), 0, stream>>>(Wk, WkT, 4096, 1024);
  transpose_cvt_k<<<dim3(32,128),  dim3(32,8), 0, stream>>>(Wv, WvT, 4096, 1024);
  transpose_cvt_k<<<dim3(128,128), dim3(32,8), 0, stream>>>(Wo, WoT, 4096, 4096);
  // projections (Q first: its weight buffer is recycled for VT); Q pre-scaled
  gemm8_k<unsigned short><<<dim3(16,16), dim3(512), 0, stream>>>(hsb, WqT, Qb, 4096, 4096, 4096, ATTN_MULT);
  gemm_bt_k<unsigned short><<<dim3(16,32), dim3(256), 0, stream>>>(hsb, WkT, KVb, 4096, 2048, 4096);
  // V (KV cols 1024..2047) -> V^T [(b*1024+c)][s]
  transpose_v_k<<<dim3(32,128), dim3(32,8), 0, stream>>>(KVb, VTb);
  // attention
  attn_k<<<dim3(256), dim3(512), 0, stream>>>(Qb, KVb, VTb, ctxb);
  // output projection (fp32 out)
  gemm8_k<float><<<dim3(16,16), dim3(512), 0, stream>>>(ctxb, WoT, (float*)d_out, 4096, 4096, 4096, 1.0f);
}

// Round 18
// 506.185 us; speedup vs baseline: 1.0343x; 1.0343x over previous
//
#include <hip/hip_runtime.h>
#include <hip/hip_bf16.h>
#include <type_traits>
#include <utility>
#include <cmath>

// ---- problem constants ----
#define HIDDEN 4096
#define NHEADS 32
#define NKV 8
#define HD 128
#define BB 2
#define SS 2048
#define NTOK (BB*SS)                  // 4096 tokens
#define ATTN_MULT 0.08838834764831845f

using bf16x8 = __attribute__((ext_vector_type(8))) short;
using f32x4  = __attribute__((ext_vector_type(4))) float;

using gas = __attribute__((address_space(1))) const void;
using las = __attribute__((address_space(3))) void;

__device__ __forceinline__ unsigned short f2bf(float f){
  unsigned int u = __builtin_bit_cast(unsigned int, f);
  u += 0x7fffu + ((u >> 16) & 1u);
  return (unsigned short)(u >> 16);
}
__device__ __forceinline__ unsigned int cvtpk(float lo, float hi){
  unsigned int r;
  asm("v_cvt_pk_bf16_f32 %0, %1, %2" : "=v"(r) : "v"(lo), "v"(hi));
  return r;
}
__device__ __forceinline__ float exp2_hw(float x){
  float r;
  asm("v_exp_f32 %0, %1" : "=v"(r) : "v"(x));
  return r;
}

// log2e-folded soft-cap poly constants: p = 2^(s*wv + B30L), wv = L + C1L*s^2 + C2L*s^4
#define LOG2E 1.4426950408889634f
#define C1L  (-5.3433149e-4f)
#define C2L  (2.3748069e-7f)
#define B30L (-43.280851227f)

// ---- fp32 -> bf16 elementwise (8 el/thread) ----
__global__ void cvt_f32_bf16_k(const float* __restrict__ in, unsigned short* __restrict__ out, int n8){
  int i = blockIdx.x * blockDim.x + threadIdx.x;
  if (i >= n8) return;
  const float4* p = (const float4*)in + (size_t)i * 2;
  float4 a = p[0], b = p[1];
  bf16x8 o;
  o[0]=f2bf(a.x); o[1]=f2bf(a.y); o[2]=f2bf(a.z); o[3]=f2bf(a.w);
  o[4]=f2bf(b.x); o[5]=f2bf(b.y); o[6]=f2bf(b.z); o[7]=f2bf(b.w);
  ((bf16x8*)out)[i] = o;
}

// ---- W[K][N] fp32 -> WT[N][K] bf16 (tiled transpose) ----
__global__ void transpose_cvt_k(const float* __restrict__ W, unsigned short* __restrict__ WT, int K, int N){
  __shared__ float tile[32][33];
  int n0 = blockIdx.x * 32, k0 = blockIdx.y * 32;
  int tx = threadIdx.x, ty = threadIdx.y; // 32 x 8
  #pragma unroll
  for (int i = 0; i < 4; ++i)
    tile[ty*4+i][tx] = W[(size_t)(k0 + ty*4 + i) * N + n0 + tx];
  __syncthreads();
  #pragma unroll
  for (int i = 0; i < 4; ++i)
    WT[(size_t)(n0 + ty*4 + i) * K + k0 + tx] = f2bf(tile[tx][ty*4+i]);
}

// ---- bf16 KV[4096][2048] (V in cols 1024..2047) -> VT[(b*1024+c)][s] ----
__global__ void transpose_v_k(const unsigned short* __restrict__ in, unsigned short* __restrict__ out){
  __shared__ unsigned short tile[32][33];
  int c0 = blockIdx.x * 32, r0 = blockIdx.y * 32;
  int tx = threadIdx.x, ty = threadIdx.y; // 32 x 8
  #pragma unroll
  for (int i = 0; i < 4; ++i)
    tile[ty*4+i][tx] = in[(size_t)(r0 + ty*4 + i) * 2048 + 1024 + c0 + tx];
  __syncthreads();
  #pragma unroll
  for (int i = 0; i < 4; ++i){
    int c = c0 + ty*4 + i, r = r0 + tx;
    out[((size_t)((r >> 11) * 1024 + c)) * 2048 + (r & 2047)] = tile[tx][ty*4+i];
  }
}

// ---- old reliable 128x128x32 GEMM (serial stage) — used for the KV proj ----
template<typename OutT>
__global__ __launch_bounds__(256, 3)
void gemm_bt_k(const unsigned short* __restrict__ A,
               const unsigned short* __restrict__ BT,
               OutT* __restrict__ C, int M, int N, int K){
  __shared__ __align__(16) unsigned short As[128*32];
  __shared__ __align__(16) unsigned short Bs[128*32];
  const int m0 = blockIdx.y * 128, n0 = blockIdx.x * 128;
  const int tid = threadIdx.x, w = tid >> 6, lane = tid & 63;
  const int wr = w >> 1, wc = w & 1;
  const int lrow = lane & 15, lk = (lane >> 4) * 8;
  const int arow = lane >> 2, acol = (lane & 3) * 8;

  f32x4 acc[4][4] = {};

  for (int k0 = 0; k0 < K; k0 += 32){
    #pragma unroll
    for (int i = 0; i < 2; ++i){
      int chunk = w*2 + i;
      const unsigned short* ga = A  + (size_t)(m0 + chunk*16 + arow) * K + k0 + acol;
      const unsigned short* gb = BT + (size_t)(n0 + chunk*16 + arow) * K + k0 + acol;
      __builtin_amdgcn_global_load_lds((gas*)ga, (las*)(As + chunk*512), 16, 0, 0);
      __builtin_amdgcn_global_load_lds((gas*)gb, (las*)(Bs + chunk*512), 16, 0, 0);
    }
    __syncthreads();
    bf16x8 af[4], bfr[4];
    #pragma unroll
    for (int m = 0; m < 4; ++m) af[m]  = *(const bf16x8*)&As[(wr*64 + m*16 + lrow)*32 + lk];
    #pragma unroll
    for (int n = 0; n < 4; ++n) bfr[n] = *(const bf16x8*)&Bs[(wc*64 + n*16 + lrow)*32 + lk];
    #pragma unroll
    for (int m = 0; m < 4; ++m)
      #pragma unroll
      for (int n = 0; n < 4; ++n)
        acc[m][n] = __builtin_amdgcn_mfma_f32_16x16x32_bf16(af[m], bfr[n], acc[m][n], 0, 0, 0);
    __syncthreads();
  }

  const int crow = (lane >> 4) * 4, ccol = lane & 15;
  #pragma unroll
  for (int m = 0; m < 4; ++m)
    #pragma unroll
    for (int n = 0; n < 4; ++n){
      size_t base = (size_t)(m0 + wr*64 + m*16 + crow) * N + n0 + wc*64 + n*16 + ccol;
      #pragma unroll
      for (int r = 0; r < 4; ++r){
        float v = acc[m][n][r];
        if constexpr (std::is_same<OutT, unsigned short>::value) C[base + (size_t)r*N] = f2bf(v);
        else                                                     C[base + (size_t)r*N] = v;
      }
    }
}

// ---- 256x256x64 GEMM, 2-phase counted vmcnt (R16) + af23 reads hoisted ----
// phA: read bf(8)+af01(8); stage Ag01+Bh0+Bh1(t+1); vmcnt(6); bar;
//      read af23(8) [Ag23_t just published]; MFMA q0q1 (af23 in its shadow).
// phB: stage Ag23(t+1); vmcnt(2); bar; MFMA q2q3 (no LDS reads on path).
// Ledger: entering phA {Ag23_t}=2; +6 -> vmcnt(6) retires Ag23_t; +2 in phB
// -> vmcnt(2) retires Ag01+B of t+1 (next phA's top reads). No drain in loop.
#define GBAR() asm volatile("s_barrier" ::: "memory")

template<typename OutT>
__global__ __launch_bounds__(512, 2)
void gemm8_k(const unsigned short* __restrict__ A,
             const unsigned short* __restrict__ BT,
             OutT* __restrict__ C, int M, int N, int K, float scale){
  __shared__ __align__(16) unsigned short As[2][256*64];
  __shared__ __align__(16) unsigned short Bs[2][256*64];

  const int nbx = N >> 8;
  const int id = blockIdx.x + blockIdx.y * nbx;
  const int nwg = nbx * (M >> 8);
  const int swz = (id & 7) * (nwg >> 3) + (id >> 3);
  const int m0 = (swz / nbx) << 8, n0 = (swz % nbx) << 8;

  const int tid = threadIdx.x, w = tid >> 6, lane = tid & 63;
  const int wm = w >> 2, wn = w & 3;
  const int lrow = lane & 15, lhi = lane >> 4;
  const int l3 = lane >> 3, k8l = lane & 7;
  const int NT = K >> 6;

  f32x4 acc[8][4] = {};
  bf16x8 bf[4][2];

  auto stageB = [&](int t, int s, int half){
    #pragma unroll
    for (int j = 0; j < 2; ++j){
      int row0 = half*128 + j*64 + w*8;              // wave-uniform
      int row = row0 + l3;
      const unsigned short* g = BT + (size_t)(n0 + row) * K + t*64 + ((k8l ^ (row & 7)) << 3);
      __builtin_amdgcn_global_load_lds((gas*)g, (las*)(&Bs[s][0] + row0*64), 16, 0, 0);
    }
  };
  auto stageA = [&](int t, int s, int g2){
    #pragma unroll
    for (int j = 0; j < 2; ++j){
      int g = g2 + j;
      int row0 = ((w >= 4) ? 128 : 0) + g*32 + (w & 3)*8;   // wave-uniform
      int row = row0 + l3;
      const unsigned short* ga = A + (size_t)(m0 + row) * K + t*64 + ((k8l ^ (row & 7)) << 3);
      __builtin_amdgcn_global_load_lds((gas*)ga, (las*)(&As[s][0] + row0*64), 16, 0, 0);
    }
  };

  // prologue: [Ag01_0, Bh0_0, Bh1_0, Ag23_0]; retire first 6 -> invariant {Ag23_0}
  stageA(0, 0, 0); stageB(0, 0, 0); stageB(0, 0, 1); stageA(0, 0, 2);
  asm volatile("s_waitcnt vmcnt(2)");
  GBAR();

  #pragma unroll 1
  for (int t = 0; t < NT; ++t){
    const int cur = t & 1, nxt = cur ^ 1;
    const bool pre = (t + 1 < NT);
    bf16x8 af01[2][2][2], af23[2][2][2];

    // ---- phase A: bf + af quadrants 0,1 ----
    #pragma unroll
    for (int nf = 0; nf < 4; ++nf)
      #pragma unroll
      for (int kk = 0; kk < 2; ++kk){
        int row = wn*64 + nf*16 + lrow;
        int c8 = (kk*4 + lhi) ^ (row & 7);
        bf[nf][kk] = *(const bf16x8*)&Bs[cur][row*64 + c8*8];
      }
    #pragma unroll
    for (int P = 0; P < 2; ++P)
      #pragma unroll
      for (int mi = 0; mi < 2; ++mi)
        #pragma unroll
        for (int kk = 0; kk < 2; ++kk){
          int row = wm*128 + P*32 + mi*16 + lrow;
          int c8 = (kk*4 + lhi) ^ (row & 7);
          af01[P][mi][kk] = *(const bf16x8*)&As[cur][row*64 + c8*8];
        }
    if (pre){
      stageA(t+1, nxt, 0); stageB(t+1, nxt, 0); stageB(t+1, nxt, 1);
      asm volatile("s_waitcnt vmcnt(6)");
    } else {
      asm volatile("s_waitcnt vmcnt(0)");
    }
    GBAR();
    // af23 reads hoisted here (Ag23_t published by the barrier above);
    // their latency hides under the q0q1 MFMA cluster.
    #pragma unroll
    for (int P = 0; P < 2; ++P)
      #pragma unroll
      for (int mi = 0; mi < 2; ++mi)
        #pragma unroll
        for (int kk = 0; kk < 2; ++kk){
          int row = wm*128 + (P+2)*32 + mi*16 + lrow;
          int c8 = (kk*4 + lhi) ^ (row & 7);
          af23[P][mi][kk] = *(const bf16x8*)&As[cur][row*64 + c8*8];
        }
    __builtin_amdgcn_s_setprio(1);
    #pragma unroll
    for (int P = 0; P < 2; ++P)
      #pragma unroll
      for (int mi = 0; mi < 2; ++mi)
        #pragma unroll
        for (int nf = 0; nf < 4; ++nf)
          #pragma unroll
          for (int kk = 0; kk < 2; ++kk)
            acc[P*2+mi][nf] = __builtin_amdgcn_mfma_f32_16x16x32_bf16(
                af01[P][mi][kk], bf[nf][kk], acc[P*2+mi][nf], 0, 0, 0);
    __builtin_amdgcn_s_setprio(0);

    // ---- phase B: pure MFMA (af23 already in registers) ----
    if (pre){
      stageA(t+1, nxt, 2);
      asm volatile("s_waitcnt vmcnt(2)");
    }
    GBAR();
    __builtin_amdgcn_s_setprio(1);
    #pragma unroll
    for (int P = 0; P < 2; ++P)
      #pragma unroll
      for (int mi = 0; mi < 2; ++mi)
        #pragma unroll
        for (int nf = 0; nf < 4; ++nf)
          #pragma unroll
          for (int kk = 0; kk < 2; ++kk)
            acc[(P+2)*2+mi][nf] = __builtin_amdgcn_mfma_f32_16x16x32_bf16(
                af23[P][mi][kk], bf[nf][kk], acc[(P+2)*2+mi][nf], 0, 0, 0);
    __builtin_amdgcn_s_setprio(0);
  }

  #pragma unroll
  for (int mf = 0; mf < 8; ++mf)
    #pragma unroll
    for (int nf = 0; nf < 4; ++nf){
      size_t base = (size_t)(m0 + wm*128 + mf*16 + lhi*4) * N + n0 + wn*64 + nf*16 + lrow;
      #pragma unroll
      for (int r = 0; r < 4; ++r){
        float v = acc[mf][nf][r] * scale;
        if constexpr (std::is_same<OutT, unsigned short>::value) C[base + (size_t)r*N] = f2bf(v);
        else                                                     C[base + (size_t)r*N] = v;
      }
    }
}

// ---- causal GQA attention: 32 q-rows/wave, sequential strip pairs (R13) ----
__global__ __launch_bounds__(512, 2)
void attn_k(const unsigned short* __restrict__ Q,
            const unsigned short* __restrict__ KVp,
            const unsigned short* __restrict__ VTp,
            unsigned short* __restrict__ ctx){
  __shared__ __align__(16) unsigned short Ks[2][64*128];   // 32 KB
  __shared__ __align__(16) unsigned short Vt[2][128*64];   // 32 KB
  __shared__ __align__(16) unsigned short Ps[8][1024];     // 16 KB: per-wave [2 qg][16 q][32 kv]

  // decode: 256 blocks = 8 xcd x (2 gsub x 4 hs x 4 fi)
  const int Wb = blockIdx.x;
  const int xcd = Wb & 7, sI = Wb >> 3;          // sI 0..31
  const int gsub = sI >> 4;
  const int inner = sI & 15;
  const int hsH = inner >> 2;                     // 0..3
  const int fi = inner & 3;                       // strip-pair index 0..3
  const int group = xcd*2 + gsub;                 // 0..15 = b*8 + kvh
  const int b = group >> 3, kvh = group & 7;
  const int h = kvh*4 + hsH;

  const int tid = threadIdx.x, w = tid >> 6, lane = tid & 63;
  const int lrow = lane & 15, lhi = lane >> 4;
  const int xorv = (lrow & 3) << 4;

  const unsigned short* Kbh  = KVp + (size_t)b * SS * 2048 + kvh * HD;
  const unsigned short* VTbh = VTp + ((size_t)b * 1024 + kvh * HD) * SS;

  auto STAGE = [&](int db, int t){
    #pragma unroll
    for (int it = 0; it < 2; ++it){
      int cbase = it*512 + w*64;       // wave-uniform
      int c = cbase + lane;            // chunk 0..1023 (16B each)
      int kkv = c >> 4, kc = c & 15;
      const unsigned short* gk = Kbh + (size_t)(t*64 + kkv) * 2048 + ((kc ^ (kkv & 7)) << 3);
      __builtin_amdgcn_global_load_lds((gas*)gk, (las*)(&Ks[db][0] + cbase*8), 16, 0, 0);
      int vd = c >> 3, vc = c & 7;
      const unsigned short* gv = VTbh + (size_t)vd * SS + t*64 + ((vc ^ ((vd ^ (vd >> 3)) & 7)) << 3);
      __builtin_amdgcn_global_load_lds((gas*)gv, (las*)(&Vt[db][0] + cbase*8), 16, 0, 0);
    }
  };

  #pragma unroll 1
  for (int ph = 0; ph < 2; ++ph){
    const int strip = ph ? (7 - fi) : fi;
    const int qwb = strip*256 + w*32;             // wave's q base (32 rows)
    const int nt = strip*4 + 4;

    // Q fragments: 32 rows per wave (2 groups of 16)
    bf16x8 qf[2][4];
    {
      const unsigned short* qb = Q + (size_t)(b*SS + qwb + lrow) * 4096 + h*HD + lhi*8;
      #pragma unroll
      for (int qg = 0; qg < 2; ++qg)
        #pragma unroll
        for (int ks = 0; ks < 4; ++ks)
          qf[qg][ks] = *(const bf16x8*)(qb + (size_t)qg*16*4096 + ks*32);
    }

    f32x4 o[8][2] = {};          // O^T frag: d = df*16+lhi*4+r, q = lrow
    float psum[2] = {0.f, 0.f};

    STAGE(0, 0);
    __syncthreads();

    for (int t = 0; t < nt; ++t){
      const int db = t & 1;
      if (t + 1 < nt) STAGE(db ^ 1, t + 1);

      if (t*64 <= qwb + 31){
        const char* Kc = (const char*)&Ks[db][0];
        const char* Vc = (const char*)&Vt[db][0];
        char* Pw = (char*)&Ps[w][0];

        auto body = [&](auto DIAG){
          #pragma unroll
          for (int hh = 0; hh < 2; ++hh){
            // QK for cf = 2hh, 2hh+1: sacc[qg][cc]; lane: q=lrow, kv=cf*16+lhi*4+r
            f32x4 sacc[2][2];
            #pragma unroll
            for (int cc = 0; cc < 2; ++cc){
              const int row = (hh*2 + cc)*16 + lrow;
              bf16x8 kf[4];
              #pragma unroll
              for (int ks = 0; ks < 4; ++ks){
                int kbyte = (row*256 + (ks*32 + lhi*8)*2) ^ ((row & 7) << 4);
                kf[ks] = *(const bf16x8*)(Kc + kbyte);
              }
              f32x4 s0 = {0.f,0.f,0.f,0.f}, s1 = {0.f,0.f,0.f,0.f};
              __builtin_amdgcn_s_setprio(1);
              #pragma unroll
              for (int ks = 0; ks < 4; ++ks){
                s0 = __builtin_amdgcn_mfma_f32_16x16x32_bf16(kf[ks], qf[0][ks], s0, 0, 0, 0);
                s1 = __builtin_amdgcn_mfma_f32_16x16x32_bf16(kf[ks], qf[1][ks], s1, 0, 0, 0);
              }
              __builtin_amdgcn_s_setprio(0);
              sacc[0][cc] = s0; sacc[1][cc] = s1;
            }

            // softmax + packed b64 P writes into 2KB/wave region
            #pragma unroll
            for (int qg = 0; qg < 2; ++qg){
              const int qglob = qwb + qg*16 + lrow;
              #pragma unroll
              for (int cc = 0; cc < 2; ++cc){
                float pv[4];
                #pragma unroll
                for (int r = 0; r < 4; ++r){
                  float s = __builtin_amdgcn_fmed3f(sacc[qg][cc][r], -25.f, 25.f);
                  float s2 = s*s, s4 = s2*s2;
                  float wv = __builtin_fmaf(s2, C1L, LOG2E);
                  wv = __builtin_fmaf(s4, C2L, wv);
                  float p = exp2_hw(__builtin_fmaf(s, wv, B30L));
                  if constexpr (decltype(DIAG)::value){
                    int kvg = t*64 + (hh*2 + cc)*16 + lhi*4 + r;
                    p = (kvg <= qglob) ? p : 0.f;
                  }
                  psum[qg] += p;
                  pv[r] = p;
                }
                uint2 pk;
                pk.x = cvtpk(pv[0], pv[1]);
                pk.y = cvtpk(pv[2], pv[3]);
                *(uint2*)(Pw + qg*1024 + lrow*64 + ((cc*32 + lhi*8) ^ xorv)) = pk;
              }
            }

            // PV for this 32-kv half
            bf16x8 pf0 = *(const bf16x8*)(Pw +        lrow*64 + ((lhi*16) ^ xorv));
            bf16x8 pf1 = *(const bf16x8*)(Pw + 1024 + lrow*64 + ((lhi*16) ^ xorv));
            __builtin_amdgcn_s_setprio(1);
            #pragma unroll
            for (int df = 0; df < 8; ++df){
              int d = df*16 + lrow;
              int vbyte = (d*128 + (hh*32 + lhi*8)*2) ^ (((d ^ (d >> 3)) & 7) << 4);
              bf16x8 vf = *(const bf16x8*)(Vc + vbyte);
              o[df][0] = __builtin_amdgcn_mfma_f32_16x16x32_bf16(vf, pf0, o[df][0], 0, 0, 0);
              o[df][1] = __builtin_amdgcn_mfma_f32_16x16x32_bf16(vf, pf1, o[df][1], 0, 0, 0);
            }
            __builtin_amdgcn_s_setprio(0);
          }
        };
        if (t == (qwb >> 6)) body(std::true_type{});
        else                 body(std::false_type{});
      }
      __syncthreads();
    }

    // reduce row sums across the 4 lhi groups; normalize; packed 8B stores
    #pragma unroll
    for (int qg = 0; qg < 2; ++qg){
      float sum = psum[qg];
      sum += __shfl_xor(sum, 16);
      sum += __shfl_xor(sum, 32);
      float inv = 1.f / sum;
      unsigned short* base = ctx + (size_t)(b*SS + qwb + qg*16 + lrow) * 4096 + h*HD + lhi*4;
      #pragma unroll
      for (int df = 0; df < 8; ++df){
        uint2 pk;
        pk.x = cvtpk(o[df][qg][0] * inv, o[df][qg][1] * inv);
        pk.y = cvtpk(o[df][qg][2] * inv, o[df][qg][3] * inv);
        *(uint2*)(base + df*16) = pk;
      }
    }
    __syncthreads();   // all waves done with LDS before next phase's STAGE
  }
}

// ---- workspace layout (bytes) ----
#define O_HSB   ((size_t)0)            // 33,554,432  hs bf16 [4096][4096]
#define O_WQT   ((size_t)33554432)     // 33,554,432  WqT bf16; later reused for VT (8MB)
#define O_WKT   ((size_t)67108864)     //  8,388,608  WkT bf16 [1024][4096]
#define O_WVT   ((size_t)75497472)     //  8,388,608  WvT bf16 [1024][4096] (contiguous after WkT)
#define O_WOT   ((size_t)83886080)     // 33,554,432  WoT bf16 [4096][4096]
#define O_Q     ((size_t)117440512)    // 33,554,432  Q bf16 [4096][4096] (pre-scaled by ATTN_MULT)
#define O_KV    ((size_t)150994944)    // 16,777,216  KV bf16 [4096][2048] (K|V)
#define O_CTX   ((size_t)167772160)    // 33,554,432  ctx bf16 [4096][4096]
#define WS_NEED ((size_t)201326592)

extern "C" void kernel_launch(void* const* d_in, const int* in_sizes, int n_in,
                              void* d_out, int out_size, void* d_ws, size_t ws_size,
                              hipStream_t stream){
  if (ws_size < WS_NEED) return;
  const float* hs = (const float*)d_in[0];
  const float* Wq = (const float*)d_in[1];
  const float* Wk = (const float*)d_in[2];
  const float* Wv = (const float*)d_in[3];
  const float* Wo = (const float*)d_in[4];
  char* ws = (char*)d_ws;
  unsigned short* hsb = (unsigned short*)(ws + O_HSB);
  unsigned short* WqT = (unsigned short*)(ws + O_WQT);
  unsigned short* WkT = (unsigned short*)(ws + O_WKT);
  unsigned short* WvT = (unsigned short*)(ws + O_WVT);
  unsigned short* WoT = (unsigned short*)(ws + O_WOT);
  unsigned short* Qb  = (unsigned short*)(ws + O_Q);
  unsigned short* KVb = (unsigned short*)(ws + O_KV);
  unsigned short* ctxb= (unsigned short*)(ws + O_CTX);
  unsigned short* VTb = (unsigned short*)(ws + O_WQT);  // reuse WqT region after Q proj

  // hs -> bf16
  cvt_f32_bf16_k<<<dim3((NTOK*HIDDEN/8)/256), dim3(256), 0, stream>>>(hs, hsb, NTOK*HIDDEN/8);
  // weights -> transposed bf16 ([N][K]); WkT/WvT contiguous -> one [2048][4096]
  transpose_cvt_k<<<dim3(128,128), dim3(32,8), 0, stream>>>(Wq, WqT, 4096, 4096);
  transpose_cvt_k<<<dim3(32,128),  dim3(32,8), 0, stream>>>(Wk, WkT, 4096, 1024);
  transpose_cvt_k<<<dim3(32,128),  dim3(32,8), 0, stream>>>(Wv, WvT, 4096, 1024);
  transpose_cvt_k<<<dim3(128,128), dim3(32,8), 0, stream>>>(Wo, WoT, 4096, 4096);
  // projections (Q first: its weight buffer is recycled for VT); Q pre-scaled
  gemm8_k<unsigned short><<<dim3(16,16), dim3(512), 0, stream>>>(hsb, WqT, Qb, 4096, 4096, 4096, ATTN_MULT);
  gemm_bt_k<unsigned short><<<dim3(16,32), dim3(256), 0, stream>>>(hsb, WkT, KVb, 4096, 2048, 4096);
  // V (KV cols 1024..2047) -> V^T [(b*1024+c)][s]
  transpose_v_k<<<dim3(32,128), dim3(32,8), 0, stream>>>(KVb, VTb);
  // attention
  attn_k<<<dim3(256), dim3(512), 0, stream>>>(Qb, KVb, VTb, ctxb);
  // output projection (fp32 out)
  gemm8_k<float><<<dim3(16,16), dim3(512), 0, stream>>>(ctxb, WoT, (float*)d_out, 4096, 4096, 4096, 1.0f);
}

// Round 19
// 499.650 us; speedup vs baseline: 1.0478x; 1.0131x over previous
//
#include <hip/hip_runtime.h>
#include <hip/hip_bf16.h>
#include <type_traits>
#include <utility>
#include <cmath>

// ---- problem constants ----
#define HIDDEN 4096
#define NHEADS 32
#define NKV 8
#define HD 128
#define BB 2
#define SS 2048
#define NTOK (BB*SS)                  // 4096 tokens
#define ATTN_MULT 0.08838834764831845f

using bf16x8 = __attribute__((ext_vector_type(8))) short;
using f32x4  = __attribute__((ext_vector_type(4))) float;

using gas = __attribute__((address_space(1))) const void;
using las = __attribute__((address_space(3))) void;

__device__ __forceinline__ unsigned short f2bf(float f){
  unsigned int u = __builtin_bit_cast(unsigned int, f);
  u += 0x7fffu + ((u >> 16) & 1u);
  return (unsigned short)(u >> 16);
}
__device__ __forceinline__ unsigned int cvtpk(float lo, float hi){
  unsigned int r;
  asm("v_cvt_pk_bf16_f32 %0, %1, %2" : "=v"(r) : "v"(lo), "v"(hi));
  return r;
}
__device__ __forceinline__ float exp2_hw(float x){
  float r;
  asm("v_exp_f32 %0, %1" : "=v"(r) : "v"(x));
  return r;
}

// log2e-folded soft-cap poly constants: p = 2^(s*wv + B30L), wv = L + C1L*s^2 + C2L*s^4
#define LOG2E 1.4426950408889634f
#define C1L  (-5.3433149e-4f)
#define C2L  (2.3748069e-7f)
#define B30L (-43.280851227f)

// ---- fp32 -> bf16 elementwise (8 el/thread) ----
__global__ void cvt_f32_bf16_k(const float* __restrict__ in, unsigned short* __restrict__ out, int n8){
  int i = blockIdx.x * blockDim.x + threadIdx.x;
  if (i >= n8) return;
  const float4* p = (const float4*)in + (size_t)i * 2;
  float4 a = p[0], b = p[1];
  bf16x8 o;
  o[0]=f2bf(a.x); o[1]=f2bf(a.y); o[2]=f2bf(a.z); o[3]=f2bf(a.w);
  o[4]=f2bf(b.x); o[5]=f2bf(b.y); o[6]=f2bf(b.z); o[7]=f2bf(b.w);
  ((bf16x8*)out)[i] = o;
}

// ---- W[K][N] fp32 -> WT[N][K] bf16 (tiled transpose) ----
__global__ void transpose_cvt_k(const float* __restrict__ W, unsigned short* __restrict__ WT, int K, int N){
  __shared__ float tile[32][33];
  int n0 = blockIdx.x * 32, k0 = blockIdx.y * 32;
  int tx = threadIdx.x, ty = threadIdx.y; // 32 x 8
  #pragma unroll
  for (int i = 0; i < 4; ++i)
    tile[ty*4+i][tx] = W[(size_t)(k0 + ty*4 + i) * N + n0 + tx];
  __syncthreads();
  #pragma unroll
  for (int i = 0; i < 4; ++i)
    WT[(size_t)(n0 + ty*4 + i) * K + k0 + tx] = f2bf(tile[tx][ty*4+i]);
}

// ---- bf16 KV[4096][2048] (V in cols 1024..2047) -> VT[(b*1024+c)][s] ----
__global__ void transpose_v_k(const unsigned short* __restrict__ in, unsigned short* __restrict__ out){
  __shared__ unsigned short tile[32][33];
  int c0 = blockIdx.x * 32, r0 = blockIdx.y * 32;
  int tx = threadIdx.x, ty = threadIdx.y; // 32 x 8
  #pragma unroll
  for (int i = 0; i < 4; ++i)
    tile[ty*4+i][tx] = in[(size_t)(r0 + ty*4 + i) * 2048 + 1024 + c0 + tx];
  __syncthreads();
  #pragma unroll
  for (int i = 0; i < 4; ++i){
    int c = c0 + ty*4 + i, r = r0 + tx;
    out[((size_t)((r >> 11) * 1024 + c)) * 2048 + (r & 2047)] = tile[tx][ty*4+i];
  }
}

// ---- old reliable 128x128x32 GEMM (serial stage) — used for the KV proj ----
template<typename OutT>
__global__ __launch_bounds__(256, 3)
void gemm_bt_k(const unsigned short* __restrict__ A,
               const unsigned short* __restrict__ BT,
               OutT* __restrict__ C, int M, int N, int K){
  __shared__ __align__(16) unsigned short As[128*32];
  __shared__ __align__(16) unsigned short Bs[128*32];
  const int m0 = blockIdx.y * 128, n0 = blockIdx.x * 128;
  const int tid = threadIdx.x, w = tid >> 6, lane = tid & 63;
  const int wr = w >> 1, wc = w & 1;
  const int lrow = lane & 15, lk = (lane >> 4) * 8;
  const int arow = lane >> 2, acol = (lane & 3) * 8;

  f32x4 acc[4][4] = {};

  for (int k0 = 0; k0 < K; k0 += 32){
    #pragma unroll
    for (int i = 0; i < 2; ++i){
      int chunk = w*2 + i;
      const unsigned short* ga = A  + (size_t)(m0 + chunk*16 + arow) * K + k0 + acol;
      const unsigned short* gb = BT + (size_t)(n0 + chunk*16 + arow) * K + k0 + acol;
      __builtin_amdgcn_global_load_lds((gas*)ga, (las*)(As + chunk*512), 16, 0, 0);
      __builtin_amdgcn_global_load_lds((gas*)gb, (las*)(Bs + chunk*512), 16, 0, 0);
    }
    __syncthreads();
    bf16x8 af[4], bfr[4];
    #pragma unroll
    for (int m = 0; m < 4; ++m) af[m]  = *(const bf16x8*)&As[(wr*64 + m*16 + lrow)*32 + lk];
    #pragma unroll
    for (int n = 0; n < 4; ++n) bfr[n] = *(const bf16x8*)&Bs[(wc*64 + n*16 + lrow)*32 + lk];
    #pragma unroll
    for (int m = 0; m < 4; ++m)
      #pragma unroll
      for (int n = 0; n < 4; ++n)
        acc[m][n] = __builtin_amdgcn_mfma_f32_16x16x32_bf16(af[m], bfr[n], acc[m][n], 0, 0, 0);
    __syncthreads();
  }

  const int crow = (lane >> 4) * 4, ccol = lane & 15;
  #pragma unroll
  for (int m = 0; m < 4; ++m)
    #pragma unroll
    for (int n = 0; n < 4; ++n){
      size_t base = (size_t)(m0 + wr*64 + m*16 + crow) * N + n0 + wc*64 + n*16 + ccol;
      #pragma unroll
      for (int r = 0; r < 4; ++r){
        float v = acc[m][n][r];
        if constexpr (std::is_same<OutT, unsigned short>::value) C[base + (size_t)r*N] = f2bf(v);
        else                                                     C[base + (size_t)r*N] = v;
      }
    }
}

// ---- 256x256x64 GEMM, 2-phase K-tile, counted vmcnt (never 0 in loop) ----
// phA: read bf(8)+af01(8); stage Ag01+Bh0+Bh1 of t+1; vmcnt(6); bar; MFMA q0q1.
// phB: read af23(8); stage Ag23 of t+1; vmcnt(2); bar; MFMA q2q3.
// FIFO ledger (invariant {Ag23_t} entering phA): phA 2+6=8 -> vmcnt(6) retires
// Ag23_t (phB's af23 data); phB 6+2=8 -> vmcnt(2) retires Ag01+B of t+1
// (t+1 phA's data). Every load gets >=1 phase of latency cover.
#define GBAR() asm volatile("s_barrier" ::: "memory")

template<typename OutT>
__global__ __launch_bounds__(512, 2)
void gemm8_k(const unsigned short* __restrict__ A,
             const unsigned short* __restrict__ BT,
             OutT* __restrict__ C, int M, int N, int K, float scale){
  __shared__ __align__(16) unsigned short As[2][256*64];
  __shared__ __align__(16) unsigned short Bs[2][256*64];

  const int nbx = N >> 8;
  const int id = blockIdx.x + blockIdx.y * nbx;
  const int nwg = nbx * (M >> 8);
  const int swz = (id & 7) * (nwg >> 3) + (id >> 3);
  const int m0 = (swz / nbx) << 8, n0 = (swz % nbx) << 8;

  const int tid = threadIdx.x, w = tid >> 6, lane = tid & 63;
  const int wm = w >> 2, wn = w & 3;
  const int lrow = lane & 15, lhi = lane >> 4;
  const int l3 = lane >> 3, k8l = lane & 7;
  const int NT = K >> 6;

  f32x4 acc[8][4] = {};
  bf16x8 bf[4][2];

  auto stageB = [&](int t, int s, int half){
    #pragma unroll
    for (int j = 0; j < 2; ++j){
      int row0 = half*128 + j*64 + w*8;              // wave-uniform
      int row = row0 + l3;
      const unsigned short* g = BT + (size_t)(n0 + row) * K + t*64 + ((k8l ^ (row & 7)) << 3);
      __builtin_amdgcn_global_load_lds((gas*)g, (las*)(&Bs[s][0] + row0*64), 16, 0, 0);
    }
  };
  auto stageA = [&](int t, int s, int g2){
    #pragma unroll
    for (int j = 0; j < 2; ++j){
      int g = g2 + j;
      int row0 = ((w >= 4) ? 128 : 0) + g*32 + (w & 3)*8;   // wave-uniform
      int row = row0 + l3;
      const unsigned short* ga = A + (size_t)(m0 + row) * K + t*64 + ((k8l ^ (row & 7)) << 3);
      __builtin_amdgcn_global_load_lds((gas*)ga, (las*)(&As[s][0] + row0*64), 16, 0, 0);
    }
  };

  // prologue: [Ag01_0, Bh0_0, Bh1_0, Ag23_0]; retire first 6 -> invariant {Ag23_0}
  stageA(0, 0, 0); stageB(0, 0, 0); stageB(0, 0, 1); stageA(0, 0, 2);
  asm volatile("s_waitcnt vmcnt(2)");
  GBAR();

  #pragma unroll 1
  for (int t = 0; t < NT; ++t){
    const int cur = t & 1, nxt = cur ^ 1;
    const bool pre = (t + 1 < NT);
    bf16x8 af[2][2][2];

    // ---- phase A: bf + af quadrants 0,1 ----
    #pragma unroll
    for (int nf = 0; nf < 4; ++nf)
      #pragma unroll
      for (int kk = 0; kk < 2; ++kk){
        int row = wn*64 + nf*16 + lrow;
        int c8 = (kk*4 + lhi) ^ (row & 7);
        bf[nf][kk] = *(const bf16x8*)&Bs[cur][row*64 + c8*8];
      }
    #pragma unroll
    for (int P = 0; P < 2; ++P)
      #pragma unroll
      for (int mi = 0; mi < 2; ++mi)
        #pragma unroll
        for (int kk = 0; kk < 2; ++kk){
          int row = wm*128 + P*32 + mi*16 + lrow;
          int c8 = (kk*4 + lhi) ^ (row & 7);
          af[P][mi][kk] = *(const bf16x8*)&As[cur][row*64 + c8*8];
        }
    if (pre){
      stageA(t+1, nxt, 0); stageB(t+1, nxt, 0); stageB(t+1, nxt, 1);
      asm volatile("s_waitcnt vmcnt(6)");
    } else {
      asm volatile("s_waitcnt vmcnt(0)");
    }
    GBAR();
    __builtin_amdgcn_s_setprio(1);
    #pragma unroll
    for (int P = 0; P < 2; ++P)
      #pragma unroll
      for (int mi = 0; mi < 2; ++mi)
        #pragma unroll
        for (int nf = 0; nf < 4; ++nf)
          #pragma unroll
          for (int kk = 0; kk < 2; ++kk)
            acc[P*2+mi][nf] = __builtin_amdgcn_mfma_f32_16x16x32_bf16(
                af[P][mi][kk], bf[nf][kk], acc[P*2+mi][nf], 0, 0, 0);
    __builtin_amdgcn_s_setprio(0);

    // ---- phase B: af quadrants 2,3 ----
    #pragma unroll
    for (int P = 0; P < 2; ++P)
      #pragma unroll
      for (int mi = 0; mi < 2; ++mi)
        #pragma unroll
        for (int kk = 0; kk < 2; ++kk){
          int row = wm*128 + (P+2)*32 + mi*16 + lrow;
          int c8 = (kk*4 + lhi) ^ (row & 7);
          af[P][mi][kk] = *(const bf16x8*)&As[cur][row*64 + c8*8];
        }
    if (pre){
      stageA(t+1, nxt, 2);
      asm volatile("s_waitcnt vmcnt(2)");
    }
    GBAR();
    __builtin_amdgcn_s_setprio(1);
    #pragma unroll
    for (int P = 0; P < 2; ++P)
      #pragma unroll
      for (int mi = 0; mi < 2; ++mi)
        #pragma unroll
        for (int nf = 0; nf < 4; ++nf)
          #pragma unroll
          for (int kk = 0; kk < 2; ++kk)
            acc[(P+2)*2+mi][nf] = __builtin_amdgcn_mfma_f32_16x16x32_bf16(
                af[P][mi][kk], bf[nf][kk], acc[(P+2)*2+mi][nf], 0, 0, 0);
    __builtin_amdgcn_s_setprio(0);
  }

  #pragma unroll
  for (int mf = 0; mf < 8; ++mf)
    #pragma unroll
    for (int nf = 0; nf < 4; ++nf){
      size_t base = (size_t)(m0 + wm*128 + mf*16 + lhi*4) * N + n0 + wn*64 + nf*16 + lrow;
      #pragma unroll
      for (int r = 0; r < 4; ++r){
        float v = acc[mf][nf][r] * scale;
        if constexpr (std::is_same<OutT, unsigned short>::value) C[base + (size_t)r*N] = f2bf(v);
        else                                                     C[base + (size_t)r*N] = v;
      }
    }
}

// ---- causal GQA attention: 32 q-rows/wave, sequential strip pairs (R13) ----
__global__ __launch_bounds__(512, 2)
void attn_k(const unsigned short* __restrict__ Q,
            const unsigned short* __restrict__ KVp,
            const unsigned short* __restrict__ VTp,
            unsigned short* __restrict__ ctx){
  __shared__ __align__(16) unsigned short Ks[2][64*128];   // 32 KB
  __shared__ __align__(16) unsigned short Vt[2][128*64];   // 32 KB
  __shared__ __align__(16) unsigned short Ps[8][1024];     // 16 KB: per-wave [2 qg][16 q][32 kv]

  // decode: 256 blocks = 8 xcd x (2 gsub x 4 hs x 4 fi)
  const int Wb = blockIdx.x;
  const int xcd = Wb & 7, sI = Wb >> 3;          // sI 0..31
  const int gsub = sI >> 4;
  const int inner = sI & 15;
  const int hsH = inner >> 2;                     // 0..3
  const int fi = inner & 3;                       // strip-pair index 0..3
  const int group = xcd*2 + gsub;                 // 0..15 = b*8 + kvh
  const int b = group >> 3, kvh = group & 7;
  const int h = kvh*4 + hsH;

  const int tid = threadIdx.x, w = tid >> 6, lane = tid & 63;
  const int lrow = lane & 15, lhi = lane >> 4;
  const int xorv = (lrow & 3) << 4;

  const unsigned short* Kbh  = KVp + (size_t)b * SS * 2048 + kvh * HD;
  const unsigned short* VTbh = VTp + ((size_t)b * 1024 + kvh * HD) * SS;

  auto STAGE = [&](int db, int t){
    #pragma unroll
    for (int it = 0; it < 2; ++it){
      int cbase = it*512 + w*64;       // wave-uniform
      int c = cbase + lane;            // chunk 0..1023 (16B each)
      int kkv = c >> 4, kc = c & 15;
      const unsigned short* gk = Kbh + (size_t)(t*64 + kkv) * 2048 + ((kc ^ (kkv & 7)) << 3);
      __builtin_amdgcn_global_load_lds((gas*)gk, (las*)(&Ks[db][0] + cbase*8), 16, 0, 0);
      int vd = c >> 3, vc = c & 7;
      const unsigned short* gv = VTbh + (size_t)vd * SS + t*64 + ((vc ^ ((vd ^ (vd >> 3)) & 7)) << 3);
      __builtin_amdgcn_global_load_lds((gas*)gv, (las*)(&Vt[db][0] + cbase*8), 16, 0, 0);
    }
  };

  #pragma unroll 1
  for (int ph = 0; ph < 2; ++ph){
    const int strip = ph ? (7 - fi) : fi;
    const int qwb = strip*256 + w*32;             // wave's q base (32 rows)
    const int nt = strip*4 + 4;

    // Q fragments: 32 rows per wave (2 groups of 16)
    bf16x8 qf[2][4];
    {
      const unsigned short* qb = Q + (size_t)(b*SS + qwb + lrow) * 4096 + h*HD + lhi*8;
      #pragma unroll
      for (int qg = 0; qg < 2; ++qg)
        #pragma unroll
        for (int ks = 0; ks < 4; ++ks)
          qf[qg][ks] = *(const bf16x8*)(qb + (size_t)qg*16*4096 + ks*32);
    }

    f32x4 o[8][2] = {};          // O^T frag: d = df*16+lhi*4+r, q = lrow
    float psum[2] = {0.f, 0.f};

    STAGE(0, 0);
    __syncthreads();

    for (int t = 0; t < nt; ++t){
      const int db = t & 1;
      if (t + 1 < nt) STAGE(db ^ 1, t + 1);

      if (t*64 <= qwb + 31){
        const char* Kc = (const char*)&Ks[db][0];
        const char* Vc = (const char*)&Vt[db][0];
        char* Pw = (char*)&Ps[w][0];

        auto body = [&](auto DIAG){
          #pragma unroll
          for (int hh = 0; hh < 2; ++hh){
            // QK for cf = 2hh, 2hh+1: sacc[qg][cc]; lane: q=lrow, kv=cf*16+lhi*4+r
            f32x4 sacc[2][2];
            #pragma unroll
            for (int cc = 0; cc < 2; ++cc){
              const int row = (hh*2 + cc)*16 + lrow;
              bf16x8 kf[4];
              #pragma unroll
              for (int ks = 0; ks < 4; ++ks){
                int kbyte = (row*256 + (ks*32 + lhi*8)*2) ^ ((row & 7) << 4);
                kf[ks] = *(const bf16x8*)(Kc + kbyte);
              }
              f32x4 s0 = {0.f,0.f,0.f,0.f}, s1 = {0.f,0.f,0.f,0.f};
              __builtin_amdgcn_s_setprio(1);
              #pragma unroll
              for (int ks = 0; ks < 4; ++ks){
                s0 = __builtin_amdgcn_mfma_f32_16x16x32_bf16(kf[ks], qf[0][ks], s0, 0, 0, 0);
                s1 = __builtin_amdgcn_mfma_f32_16x16x32_bf16(kf[ks], qf[1][ks], s1, 0, 0, 0);
              }
              __builtin_amdgcn_s_setprio(0);
              sacc[0][cc] = s0; sacc[1][cc] = s1;
            }

            // softmax + packed b64 P writes into 2KB/wave region
            #pragma unroll
            for (int qg = 0; qg < 2; ++qg){
              const int qglob = qwb + qg*16 + lrow;
              #pragma unroll
              for (int cc = 0; cc < 2; ++cc){
                float pv[4];
                #pragma unroll
                for (int r = 0; r < 4; ++r){
                  float s = __builtin_amdgcn_fmed3f(sacc[qg][cc][r], -25.f, 25.f);
                  float s2 = s*s, s4 = s2*s2;
                  float wv = __builtin_fmaf(s2, C1L, LOG2E);
                  wv = __builtin_fmaf(s4, C2L, wv);
                  float p = exp2_hw(__builtin_fmaf(s, wv, B30L));
                  if constexpr (decltype(DIAG)::value){
                    int kvg = t*64 + (hh*2 + cc)*16 + lhi*4 + r;
                    p = (kvg <= qglob) ? p : 0.f;
                  }
                  psum[qg] += p;
                  pv[r] = p;
                }
                uint2 pk;
                pk.x = cvtpk(pv[0], pv[1]);
                pk.y = cvtpk(pv[2], pv[3]);
                *(uint2*)(Pw + qg*1024 + lrow*64 + ((cc*32 + lhi*8) ^ xorv)) = pk;
              }
            }

            // PV for this 32-kv half
            bf16x8 pf0 = *(const bf16x8*)(Pw +        lrow*64 + ((lhi*16) ^ xorv));
            bf16x8 pf1 = *(const bf16x8*)(Pw + 1024 + lrow*64 + ((lhi*16) ^ xorv));
            __builtin_amdgcn_s_setprio(1);
            #pragma unroll
            for (int df = 0; df < 8; ++df){
              int d = df*16 + lrow;
              int vbyte = (d*128 + (hh*32 + lhi*8)*2) ^ (((d ^ (d >> 3)) & 7) << 4);
              bf16x8 vf = *(const bf16x8*)(Vc + vbyte);
              o[df][0] = __builtin_amdgcn_mfma_f32_16x16x32_bf16(vf, pf0, o[df][0], 0, 0, 0);
              o[df][1] = __builtin_amdgcn_mfma_f32_16x16x32_bf16(vf, pf1, o[df][1], 0, 0, 0);
            }
            __builtin_amdgcn_s_setprio(0);
          }
        };
        if (t == (qwb >> 6)) body(std::true_type{});
        else                 body(std::false_type{});
      }
      __syncthreads();
    }

    // reduce row sums across the 4 lhi groups; normalize; packed 8B stores
    #pragma unroll
    for (int qg = 0; qg < 2; ++qg){
      float sum = psum[qg];
      sum += __shfl_xor(sum, 16);
      sum += __shfl_xor(sum, 32);
      float inv = 1.f / sum;
      unsigned short* base = ctx + (size_t)(b*SS + qwb + qg*16 + lrow) * 4096 + h*HD + lhi*4;
      #pragma unroll
      for (int df = 0; df < 8; ++df){
        uint2 pk;
        pk.x = cvtpk(o[df][qg][0] * inv, o[df][qg][1] * inv);
        pk.y = cvtpk(o[df][qg][2] * inv, o[df][qg][3] * inv);
        *(uint2*)(base + df*16) = pk;
      }
    }
    __syncthreads();   // all waves done with LDS before next phase's STAGE
  }
}

// ---- workspace layout (bytes) ----
#define O_HSB   ((size_t)0)            // 33,554,432  hs bf16 [4096][4096]
#define O_WQT   ((size_t)33554432)     // 33,554,432  WqT bf16; later reused for VT (8MB)
#define O_WKT   ((size_t)67108864)     //  8,388,608  WkT bf16 [1024][4096]
#define O_WVT   ((size_t)75497472)     //  8,388,608  WvT bf16 [1024][4096] (contiguous after WkT)
#define O_WOT   ((size_t)83886080)     // 33,554,432  WoT bf16 [4096][4096]
#define O_Q     ((size_t)117440512)    // 33,554,432  Q bf16 [4096][4096] (pre-scaled by ATTN_MULT)
#define O_KV    ((size_t)150994944)    // 16,777,216  KV bf16 [4096][2048] (K|V)
#define O_CTX   ((size_t)167772160)    // 33,554,432  ctx bf16 [4096][4096]
#define WS_NEED ((size_t)201326592)

extern "C" void kernel_launch(void* const* d_in, const int* in_sizes, int n_in,
                              void* d_out, int out_size, void* d_ws, size_t ws_size,
                              hipStream_t stream){
  if (ws_size < WS_NEED) return;
  const float* hs = (const float*)d_in[0];
  const float* Wq = (const float*)d_in[1];
  const float* Wk = (const float*)d_in[2];
  const float* Wv = (const float*)d_in[3];
  const float* Wo = (const float*)d_in[4];
  char* ws = (char*)d_ws;
  unsigned short* hsb = (unsigned short*)(ws + O_HSB);
  unsigned short* WqT = (unsigned short*)(ws + O_WQT);
  unsigned short* WkT = (unsigned short*)(ws + O_WKT);
  unsigned short* WvT = (unsigned short*)(ws + O_WVT);
  unsigned short* WoT = (unsigned short*)(ws + O_WOT);
  unsigned short* Qb  = (unsigned short*)(ws + O_Q);
  unsigned short* KVb = (unsigned short*)(ws + O_KV);
  unsigned short* ctxb= (unsigned short*)(ws + O_CTX);
  unsigned short* VTb = (unsigned short*)(ws + O_WQT);  // reuse WqT region after Q proj

  // hs -> bf16
  cvt_f32_bf16_k<<<dim3((NTOK*HIDDEN/8)/256), dim3(256), 0, stream>>>(hs, hsb, NTOK*HIDDEN/8);
  // weights -> transposed bf16 ([N][K]); WkT/WvT contiguous -> one [2048][4096]
  transpose_cvt_k<<<dim3(128,128), dim3(32,8), 0, stream>>>(Wq, WqT, 4096, 4096);
  transpose_cvt_k<<<dim3(32,128),  dim3(32,8), 0, stream>>>(Wk, WkT, 4096, 1024);
  transpose_cvt_k<<<dim3(32,128),  dim3(32,8), 0, stream>>>(Wv, WvT, 4096, 1024);
  transpose_cvt_k<<<dim3(128,128), dim3(32,8), 0, stream>>>(Wo, WoT, 4096, 4096);
  // projections (Q first: its weight buffer is recycled for VT); Q pre-scaled
  gemm8_k<unsigned short><<<dim3(16,16), dim3(512), 0, stream>>>(hsb, WqT, Qb, 4096, 4096, 4096, ATTN_MULT);
  gemm_bt_k<unsigned short><<<dim3(16,32), dim3(256), 0, stream>>>(hsb, WkT, KVb, 4096, 2048, 4096);
  // V (KV cols 1024..2047) -> V^T [(b*1024+c)][s]
  transpose_v_k<<<dim3(32,128), dim3(32,8), 0, stream>>>(KVb, VTb);
  // attention
  attn_k<<<dim3(256), dim3(512), 0, stream>>>(Qb, KVb, VTb, ctxb);
  // output projection (fp32 out)
  gemm8_k<float><<<dim3(16,16), dim3(512), 0, stream>>>(ctxb, WoT, (float*)d_out, 4096, 4096, 4096, 1.0f);
}